// Round 1
// baseline (1429.814 us; speedup 1.0000x reference)
//
#include <hip/hip_runtime.h>

#define NN 100000
#define NE 3200000
#define FIN 64
#define FH 32
#define FO 5

// Detect whether edge_index arrived as int64 (odd 32-bit words all zero) or int32.
__global__ void k_detect(const int* __restrict__ ei, int* __restrict__ flag) {
    int v = ei[2 * (int)threadIdx.x + 1];
    unsigned long long m = __ballot(v == 0);
    if (threadIdx.x == 0) flag[0] = (m == ~0ULL) ? 1 : 0;
}

__global__ void k_deg_init(float* __restrict__ deg) {
    int n = blockIdx.x * 256 + threadIdx.x;
    if (n < NN) deg[n] = 1.0f;  // self-loop weight
}

__global__ void k_deg_scatter(const int* __restrict__ ei, const float* __restrict__ w,
                              float* __restrict__ deg, const int* __restrict__ flag) {
    int e = blockIdx.x * 256 + threadIdx.x;
    if (e >= NE) return;
    int is64 = flag[0];
    int st = is64 ? 2 : 1;
    int db = is64 ? 2 * NE : NE;
    int dst = ei[db + e * st];
    atomicAdd(&deg[dst], w[e]);
}

__global__ void k_dinv(float* __restrict__ deg) {
    int n = blockIdx.x * 256 + threadIdx.x;
    if (n < NN) {
        float d = deg[n];
        deg[n] = (d > 0.f) ? rsqrtf(d) : 0.f;
    }
}

// hs1[n,h] = dinv[n] * sum_f x[n,f]*W1[f,h]; acc1 initialized with self-loop term (= hs1)
__global__ void k_gemm1(const float* __restrict__ x, const float* __restrict__ W1,
                        const float* __restrict__ dinv, float* __restrict__ hs1,
                        float* __restrict__ acc1) {
    __shared__ float Ws[FIN * FH];  // 8 KB
    __shared__ float Xs[8 * FIN];   // 2 KB
    int tid = threadIdx.x;
    for (int i = tid; i < FIN * FH; i += 256) Ws[i] = W1[i];
    int row0 = blockIdx.x * 8;
    for (int i = tid; i < 8 * FIN; i += 256) {
        int r = i >> 6, f = i & 63;
        Xs[i] = x[(row0 + r) * FIN + f];
    }
    __syncthreads();
    int h = tid & 31, r = tid >> 5;
    int n = row0 + r;
    float acc = 0.f;
#pragma unroll
    for (int f = 0; f < FIN; ++f) acc += Xs[r * FIN + f] * Ws[f * FH + h];
    float v = dinv[n] * acc;
    hs1[n * FH + h] = v;
    acc1[n * FH + h] = v;
}

// 32 lanes per edge: acc1[dst,h] += w_e * hs1[src,h]
__global__ void k_scatter1(const int* __restrict__ ei, const float* __restrict__ w,
                           const float* __restrict__ hs1, float* __restrict__ acc1,
                           const int* __restrict__ flag) {
    int t = blockIdx.x * 256 + threadIdx.x;
    int e = t >> 5;
    int h = t & 31;
    int is64 = flag[0];
    int st = is64 ? 2 : 1;
    int db = is64 ? 2 * NE : NE;
    int src = ei[e * st];
    int dst = ei[db + e * st];
    float val = w[e] * hs1[src * FH + h];
    atomicAdd(&acc1[dst * FH + h], val);
}

__global__ void k_finish1(const float* __restrict__ acc1, const float* __restrict__ dinv,
                          const float* __restrict__ b1, float* __restrict__ x1out) {
    int t = blockIdx.x * 256 + threadIdx.x;  // grid covers NN*FH exactly
    int n = t >> 5, h = t & 31;
    float v = dinv[n] * acc1[t] + b1[h];
    x1out[t] = (v > 0.f) ? v : 0.f;
}

// hs2[n,c] = dinv[n] * sum_h x1[n,h]*W2[h,c]; acc2 init = hs2
__global__ void k_gemm2(const float* __restrict__ x1, const float* __restrict__ W2,
                        const float* __restrict__ dinv, float* __restrict__ hs2,
                        float* __restrict__ acc2) {
    __shared__ float Ws[FH * FO];  // 160 floats
    int tid = threadIdx.x;
    if (tid < FH * FO) Ws[tid] = W2[tid];
    __syncthreads();
    int n = blockIdx.x * 256 + tid;
    if (n >= NN) return;
    float a0 = 0.f, a1 = 0.f, a2 = 0.f, a3 = 0.f, a4 = 0.f;
    const float* xr = x1 + n * FH;
#pragma unroll
    for (int h = 0; h < FH; ++h) {
        float xv = xr[h];
        a0 += xv * Ws[h * FO + 0];
        a1 += xv * Ws[h * FO + 1];
        a2 += xv * Ws[h * FO + 2];
        a3 += xv * Ws[h * FO + 3];
        a4 += xv * Ws[h * FO + 4];
    }
    float di = dinv[n];
    float* o = hs2 + n * FO;
    float* a = acc2 + n * FO;
    o[0] = di * a0; a[0] = di * a0;
    o[1] = di * a1; a[1] = di * a1;
    o[2] = di * a2; a[2] = di * a2;
    o[3] = di * a3; a[3] = di * a3;
    o[4] = di * a4; a[4] = di * a4;
}

// thread per edge: acc2[dst,c] += w_e * hs2[src,c]
__global__ void k_scatter2(const int* __restrict__ ei, const float* __restrict__ w,
                           const float* __restrict__ hs2, float* __restrict__ acc2,
                           const int* __restrict__ flag) {
    int e = blockIdx.x * 256 + threadIdx.x;
    if (e >= NE) return;
    int is64 = flag[0];
    int st = is64 ? 2 : 1;
    int db = is64 ? 2 * NE : NE;
    int src = ei[e * st];
    int dst = ei[db + e * st];
    float we = w[e];
    const float* s = hs2 + src * FO;
    float* d = acc2 + dst * FO;
#pragma unroll
    for (int c = 0; c < FO; ++c) atomicAdd(&d[c], we * s[c]);
}

__global__ void k_finish2(const float* __restrict__ acc2, const float* __restrict__ dinv,
                          const float* __restrict__ b2, float* __restrict__ out) {
    int t = blockIdx.x * 256 + threadIdx.x;
    if (t >= NN * FO) return;
    int n = t / FO, c = t % FO;
    out[t] = dinv[n] * acc2[t] + b2[c];
}

extern "C" void kernel_launch(void* const* d_in, const int* in_sizes, int n_in,
                              void* d_out, int out_size, void* d_ws, size_t ws_size,
                              hipStream_t stream) {
    const float* x  = (const float*)d_in[0];
    const int*   ei = (const int*)d_in[1];
    const float* w  = (const float*)d_in[2];
    const float* W1 = (const float*)d_in[3];
    const float* b1 = (const float*)d_in[4];
    const float* W2 = (const float*)d_in[5];
    const float* b2 = (const float*)d_in[6];
    float* out = (float*)d_out;  // x2 in [0, 5N), x1 in [5N, 37N)
    float* ws  = (float*)d_ws;

    float* dinv = ws;                    // N   (deg, then rsqrt in place)
    float* hs1  = ws + NN;               // 32N
    float* acc1 = ws + NN + 32 * NN;     // 32N
    float* hs2  = ws + NN;               // 5N (reuses hs1 region, layer 1 done)
    float* acc2 = ws + NN + 5 * NN;      // 5N
    int*   flag = (int*)(ws + NN + 64 * NN);  // 1 int @ 65N floats (~26 MB total)

    float* x1 = out + NN * FO;

    k_detect<<<1, 64, 0, stream>>>(ei, flag);
    k_deg_init<<<(NN + 255) / 256, 256, 0, stream>>>(dinv);
    k_deg_scatter<<<(NE + 255) / 256, 256, 0, stream>>>(ei, w, dinv, flag);
    k_dinv<<<(NN + 255) / 256, 256, 0, stream>>>(dinv);
    k_gemm1<<<NN / 8, 256, 0, stream>>>(x, W1, dinv, hs1, acc1);
    k_scatter1<<<(NE * 32) / 256, 256, 0, stream>>>(ei, w, hs1, acc1, flag);
    k_finish1<<<(NN * FH) / 256, 256, 0, stream>>>(acc1, dinv, b1, x1);
    k_gemm2<<<(NN + 255) / 256, 256, 0, stream>>>(x1, W2, dinv, hs2, acc2);
    k_scatter2<<<(NE + 255) / 256, 256, 0, stream>>>(ei, w, hs2, acc2, flag);
    k_finish2<<<(NN * FO + 255) / 256, 256, 0, stream>>>(acc2, dinv, b2, out);
}

// Round 2
// 712.681 us; speedup vs baseline: 2.0062x; 2.0062x over previous
//
#include <hip/hip_runtime.h>

#define NN 100000
#define NE 3200000
#define FIN 64
#define FH 32
#define FO 5
#define NBLK_A 391   // ceil(NN/256)

// ---------- edge dtype detect (int64 vs int32) ----------
__global__ void k_detect(const int* __restrict__ ei, int* __restrict__ flag) {
    int v = ei[2 * (int)threadIdx.x + 1];
    unsigned long long m = __ballot(v == 0);
    if (threadIdx.x == 0) flag[0] = (m == ~0ULL) ? 1 : 0;
}

__global__ void k_zero(int* __restrict__ p) {
    int i = blockIdx.x * 256 + threadIdx.x;
    if (i < NN) p[i] = 0;
}

// ---------- CSR build: histogram of dst ----------
__global__ void k_hist(const int* __restrict__ ei, int* __restrict__ cnt,
                       const int* __restrict__ flag) {
    int e = blockIdx.x * 256 + threadIdx.x;
    if (e >= NE) return;
    int is64 = flag[0];
    int dst = is64 ? ei[2 * NE + 2 * e] : ei[NE + e];
    atomicAdd(&cnt[dst], 1);
}

// ---------- two-level exclusive scan ----------
__global__ void k_scanA(const int* __restrict__ cnt, int* __restrict__ rowptr,
                        int* __restrict__ bsum) {
    __shared__ int s[256];
    int t = threadIdx.x;
    int gid = blockIdx.x * 256 + t;
    int v = (gid < NN) ? cnt[gid] : 0;
    s[t] = v;
    __syncthreads();
    for (int off = 1; off < 256; off <<= 1) {
        int x = (t >= off) ? s[t - off] : 0;
        __syncthreads();
        s[t] += x;
        __syncthreads();
    }
    if (gid < NN) rowptr[gid] = s[t] - v;  // block-local exclusive
    if (t == 255) bsum[blockIdx.x] = s[255];
}

__global__ void k_scanB(const int* __restrict__ bsum, int* __restrict__ bscan,
                        int* __restrict__ rowptr) {
    __shared__ int s[512];
    int t = threadIdx.x;
    int v = (t < NBLK_A) ? bsum[t] : 0;
    s[t] = v;
    __syncthreads();
    for (int off = 1; off < 512; off <<= 1) {
        int x = (t >= off) ? s[t - off] : 0;
        __syncthreads();
        s[t] += x;
        __syncthreads();
    }
    bscan[t] = s[t] - v;  // exclusive
    if (t == NBLK_A - 1) rowptr[NN] = s[t];  // total = NE
}

__global__ void k_scanC(int* __restrict__ rowptr, const int* __restrict__ bscan,
                        int* __restrict__ fillpos) {
    int gid = blockIdx.x * 256 + threadIdx.x;
    if (gid >= NN) return;
    int v = rowptr[gid] + bscan[gid >> 8];
    rowptr[gid] = v;
    fillpos[gid] = v;
}

// ---------- fill CSR: edata[pos] = (src, w_bits) ----------
__global__ void k_fill(const int* __restrict__ ei, const float* __restrict__ w,
                       int* __restrict__ fillpos, int2* __restrict__ edata,
                       const int* __restrict__ flag) {
    int e = blockIdx.x * 256 + threadIdx.x;
    if (e >= NE) return;
    int is64 = flag[0];
    int src, dst;
    if (is64) { src = ei[2 * e]; dst = ei[2 * NE + 2 * e]; }
    else      { src = ei[e];     dst = ei[NE + e]; }
    int pos = atomicAdd(&fillpos[dst], 1);
    edata[pos] = make_int2(src, __float_as_int(w[e]));
}

// ---------- dinv[n] = rsqrt(1 + sum of in-edge weights) ----------
__global__ void k_dinv(const int* __restrict__ rowptr, const int2* __restrict__ edata,
                       float* __restrict__ dinv) {
    int t = blockIdx.x * 256 + threadIdx.x;
    int n = t >> 3;          // 8 lanes per node, 32 nodes/block
    int l = t & 7;
    int start = rowptr[n], end = rowptr[n + 1];
    float s = 0.f;
    for (int i = start + l; i < end; i += 8) s += __int_as_float(edata[i].y);
    for (int k = 4; k >= 1; k >>= 1) s += __shfl_down(s, k, 8);
    if (l == 0) dinv[n] = rsqrtf(1.0f + s);
}

// ---------- hs1[n,h] = dinv[n] * (x @ W1)[n,h] ----------
__global__ void k_gemm1(const float* __restrict__ x, const float* __restrict__ W1,
                        const float* __restrict__ dinv, float* __restrict__ hs1) {
    __shared__ float Ws[FIN * FH];  // 8 KB
    __shared__ float Xs[8 * FIN];   // 2 KB
    int tid = threadIdx.x;
    for (int i = tid; i < FIN * FH; i += 256) Ws[i] = W1[i];
    int row0 = blockIdx.x * 8;
    for (int i = tid; i < 8 * FIN; i += 256) {
        int r = i >> 6, f = i & 63;
        Xs[i] = x[(row0 + r) * FIN + f];
    }
    __syncthreads();
    int h = tid & 31, r = tid >> 5;
    int n = row0 + r;
    float acc = 0.f;
#pragma unroll
    for (int f = 0; f < FIN; ++f) acc += Xs[r * FIN + f] * Ws[f * FH + h];
    hs1[n * FH + h] = dinv[n] * acc;
}

// ---------- pull aggregation layer 1 + bias + relu ----------
__global__ void k_pull1(const int* __restrict__ rowptr, const int2* __restrict__ edata,
                        const float* __restrict__ hs1, const float* __restrict__ dinv,
                        const float* __restrict__ b1, float* __restrict__ x1out) {
    int tid = threadIdx.x;
    int h = tid & 31;
    int n = blockIdx.x * 8 + (tid >> 5);
    int start = rowptr[n], end = rowptr[n + 1];
    float acc = hs1[n * FH + h];  // self-loop (w=1)
    for (int i = start; i < end; ++i) {
        int2 ed = edata[i];
        acc += __int_as_float(ed.y) * hs1[ed.x * FH + h];
    }
    float v = dinv[n] * acc + b1[h];
    x1out[n * FH + h] = (v > 0.f) ? v : 0.f;
}

// ---------- hs2[n,c] = dinv[n] * (x1 @ W2)[n,c] ----------
__global__ void k_gemm2(const float* __restrict__ x1, const float* __restrict__ W2,
                        const float* __restrict__ dinv, float* __restrict__ hs2) {
    __shared__ float Ws[FH * FO];
    int tid = threadIdx.x;
    if (tid < FH * FO) Ws[tid] = W2[tid];
    __syncthreads();
    int n = blockIdx.x * 256 + tid;
    if (n >= NN) return;
    float a0 = 0.f, a1 = 0.f, a2 = 0.f, a3 = 0.f, a4 = 0.f;
    const float* xr = x1 + n * FH;
#pragma unroll
    for (int h = 0; h < FH; ++h) {
        float xv = xr[h];
        a0 += xv * Ws[h * FO + 0];
        a1 += xv * Ws[h * FO + 1];
        a2 += xv * Ws[h * FO + 2];
        a3 += xv * Ws[h * FO + 3];
        a4 += xv * Ws[h * FO + 4];
    }
    float di = dinv[n];
    float* o = hs2 + n * FO;
    o[0] = di * a0; o[1] = di * a1; o[2] = di * a2; o[3] = di * a3; o[4] = di * a4;
}

// ---------- pull aggregation layer 2 + bias ----------
__global__ void k_pull2(const int* __restrict__ rowptr, const int2* __restrict__ edata,
                        const float* __restrict__ hs2, const float* __restrict__ dinv,
                        const float* __restrict__ b2, float* __restrict__ out) {
    int tid = threadIdx.x;
    int c = tid & 7;          // 8 lanes/node, 5 active
    int n = blockIdx.x * 32 + (tid >> 3);
    int start = rowptr[n], end = rowptr[n + 1];
    float acc = (c < FO) ? hs2[n * FO + c] : 0.f;
    for (int i = start; i < end; ++i) {
        int2 ed = edata[i];
        if (c < FO) acc += __int_as_float(ed.y) * hs2[ed.x * FO + c];
    }
    if (c < FO) out[n * FO + c] = dinv[n] * acc + b2[c];
}

extern "C" void kernel_launch(void* const* d_in, const int* in_sizes, int n_in,
                              void* d_out, int out_size, void* d_ws, size_t ws_size,
                              hipStream_t stream) {
    const float* x  = (const float*)d_in[0];
    const int*   ei = (const int*)d_in[1];
    const float* w  = (const float*)d_in[2];
    const float* W1 = (const float*)d_in[3];
    const float* b1 = (const float*)d_in[4];
    const float* W2 = (const float*)d_in[5];
    const float* b2 = (const float*)d_in[6];
    float* out = (float*)d_out;  // x2 in [0,5N), x1 in [5N,37N)
    float* ws  = (float*)d_ws;

    // workspace layout (floats)
    float* dinv    = ws;                         // NN
    float* hs1     = ws + NN;                    // 32*NN
    float* hs2     = ws + 33 * NN;               // 5*NN
    int*   cnt     = (int*)(ws + 38 * NN);       // NN
    int*   rowptr  = (int*)(ws + 39 * NN);       // NN+1
    int*   fillpos = (int*)(ws + 40 * NN + 64);  // NN
    int*   bsum    = (int*)(ws + 41 * NN + 128); // 512
    int*   bscan   = (int*)(ws + 41 * NN + 1024);// 512
    int*   flag    = (int*)(ws + 41 * NN + 2048);// 1
    int2*  edata   = (int2*)(ws + 42 * NN);      // NE int2 (8B-aligned: 42*NN even)

    float* x1 = out + NN * FO;

    k_detect<<<1, 64, 0, stream>>>(ei, flag);
    k_zero<<<NBLK_A, 256, 0, stream>>>(cnt);
    k_hist<<<NE / 256, 256, 0, stream>>>(ei, cnt, flag);
    k_scanA<<<NBLK_A, 256, 0, stream>>>(cnt, rowptr, bsum);
    k_scanB<<<1, 512, 0, stream>>>(bsum, bscan, rowptr);
    k_scanC<<<NBLK_A, 256, 0, stream>>>(rowptr, bscan, fillpos);
    k_fill<<<NE / 256, 256, 0, stream>>>(ei, w, fillpos, edata, flag);
    k_dinv<<<NN / 32, 256, 0, stream>>>(rowptr, edata, dinv);
    k_gemm1<<<NN / 8, 256, 0, stream>>>(x, W1, dinv, hs1);
    k_pull1<<<NN / 8, 256, 0, stream>>>(rowptr, edata, hs1, dinv, b1, x1);
    k_gemm2<<<NBLK_A, 256, 0, stream>>>(x1, W2, dinv, hs2);
    k_pull2<<<NN / 32, 256, 0, stream>>>(rowptr, edata, hs2, dinv, b2, out);
}